// Round 3
// baseline (439.158 us; speedup 1.0000x reference)
//
#include <hip/hip_runtime.h>
#include <hip/hip_cooperative_groups.h>
#include <stdint.h>

namespace cg = cooperative_groups;

typedef unsigned int u32;
typedef unsigned long long u64;

#define F_UPPER 0.4f
#define F_LOWER 0.1f
#define MAX_POS 2048
#define NB 512
#define NT 256
#define L_SZ 65536
#define M_SZ 512
#define C_SZ 21
#define NBINS 8192
#define CAND_CAP 1024

struct State {
  double sum_pos_ce;
  double sum_neg_ce;
  double bbox_sum;
  int num_pos;
  int num_neg;
  int select_all;
  int sel_k;
  u32 cand_cnt;
  u32 _pad;
  u64 prefix;
};

struct Params {
  const float* rois; const float* scores; const float* deltas;
  const float4* gtb; const int* gtc; float* out;
  State* st; u64* gkey; u32* hist0; int* scat;
  float4* pred; float* lse; u64* rowkey; int* matches; u32* u23;
  int* blockcnt; float4* pp; float4* gp; u64* cand;
};

__device__ __forceinline__ float area_fn(const float4 a) {
#pragma clang fp contract(off)
  return (a.z - a.x + 1.0f) * (a.w - a.y + 1.0f);
}

__device__ __forceinline__ float sl1(float d) {
#pragma clang fp contract(off)
  float ad = fabsf(d);
  return (ad < 0.01f) ? (50.0f * d * d) : (ad - 0.005f);
}

__device__ __forceinline__ u32 rotl(u32 x, int d) { return (x << d) | (x >> (32 - d)); }

// JAX threefry2x32, key=(0,42); counts = iota(L) split in halves.
__device__ u32 threefry_bits(u32 i, u32 H) {
  u32 x0, x1; bool hi;
  if (i < H) { x0 = i;     x1 = i + H; hi = false; }
  else       { x0 = i - H; x1 = i;     hi = true;  }
  const u32 ks0 = 0u, ks1 = 42u;
  const u32 ks2 = ks0 ^ ks1 ^ 0x1BD11BDAu;
  x0 += ks0; x1 += ks1;
#define RND(r) { x0 += x1; x1 = rotl(x1, r); x1 ^= x0; }
  RND(13) RND(15) RND(26) RND(6)   x0 += ks1; x1 += ks2 + 1u;
  RND(17) RND(29) RND(16) RND(24)  x0 += ks2; x1 += ks0 + 2u;
  RND(13) RND(15) RND(26) RND(6)   x0 += ks0; x1 += ks1 + 3u;
  RND(17) RND(29) RND(16) RND(24)  x0 += ks1; x1 += ks2 + 4u;
  RND(13) RND(15) RND(26) RND(6)   x0 += ks2; x1 += ks0 + 5u;
#undef RND
  return hi ? x1 : x0;
}

__global__ void __launch_bounds__(NT, 2) mega(Params P) {
  cg::grid_group grid = cg::this_grid();
  const int tid = threadIdx.x;
  const int b = blockIdx.x;

  __shared__ float4 sg[M_SZ];        // gt boxes (8KB); reused: pairs j-tile, cand buffer
  __shared__ float  ga[M_SZ];        // gt areas
  __shared__ u64    scol[M_SZ];      // per-block column max
  __shared__ u64    srow[128];       // per-pred row merge; reused P2
  __shared__ float4 spred[128];
  __shared__ float  sarea[128];
  __shared__ float  ssc[128 * C_SZ]; // score staging
  __shared__ float  sro[128 * 5];    // roi staging
  __shared__ int    sscan[NT];
  __shared__ int    swsum[4];
  __shared__ double sdacc[4];
  __shared__ u64    sth;

  // ================= P1: ROI + IoU (each IoU computed once) =================
  {
    const int pbase = b << 7;
    for (int k = tid; k < 128 * C_SZ; k += NT) ssc[k] = P.scores[(size_t)pbase * C_SZ + k];
    for (int k = tid; k < 128 * 5; k += NT)    sro[k] = P.rois[(size_t)pbase * 5 + k];
    for (int j = tid; j < M_SZ; j += NT) {
      float4 g = P.gtb[j];
      sg[j] = g; ga[j] = area_fn(g); scol[j] = 0ull;
    }
    if (tid < 128) srow[tid] = 0ull;
    __syncthreads();
    if (tid < 128) {
      int i = pbase + tid;
      const float* sr = ssc + tid * C_SZ;
      float mx = sr[0]; int mi = 0;
      for (int j = 1; j < C_SZ; ++j) { float v = sr[j]; if (v > mx) { mx = v; mi = j; } }
      float s = 0.0f;
      for (int j = 0; j < C_SZ; ++j) s += expf(sr[j] - mx);
      P.lse[i] = mx + logf(s);
      float4 d = *(const float4*)(P.deltas + (size_t)i * (4 * C_SZ) + 4 * mi);
      const float* r = sro + tid * 5;
      float4 pb;
      pb.x = r[1] + d.x; pb.y = r[2] + d.y; pb.z = r[3] + d.z; pb.w = r[4] + d.w;
      spred[tid] = pb; sarea[tid] = area_fn(pb);
      P.pred[i] = pb;
    }
    __syncthreads();
    const int p = tid & 127;
    const int c256 = (tid >> 7) << 8;
    const float4 pb = spred[p];
    const float pa = sarea[p];
    const u32 collo = 0xFFFFFFFFu - (u32)(pbase + p);
    u64 rbest = 0ull;
#pragma unroll 4
    for (int jj = 0; jj < 256; ++jj) {
#pragma clang fp contract(off)
      int j = c256 | ((p + jj) & 255);
      float4 gb = sg[j];
      float iw = fminf(pb.z, gb.z) - fmaxf(pb.x, gb.x) + 1.0f;
      iw = fmaxf(iw, 0.0f);
      float ih = fminf(pb.w, gb.w) - fmaxf(pb.y, gb.y) + 1.0f;
      ih = fmaxf(ih, 0.0f);
      float inter = iw * ih;
      float den = pa + ga[j] - inter;
      float v = inter * __builtin_amdgcn_rcpf(den);
      u32 bits = __float_as_uint(v);
      u64 rk = ((u64)bits << 32) | (u32)(0xFFFFFFFFu - (u32)j);
      if (rk > rbest) rbest = rk;
      atomicMax(&scol[j], ((u64)bits << 32) | collo);  // LDS ds_max_u64
    }
    atomicMax(&srow[p], rbest);
    __syncthreads();
    if (tid < 128) P.rowkey[pbase + tid] = srow[tid];
    for (int j = tid; j < M_SZ; j += NT) atomicMax(&P.gkey[j], scol[j]);
  }
  grid.sync();  // A

  // ================= P2: gt-argmax scatter =================
  if (b == 0) {
    for (int g = tid; g < M_SZ; g += NT) {
      u64 key = P.gkey[g];
      int pidx = (int)(0xFFFFFFFFu - (u32)key);
      atomicMax(&P.scat[pidx], g);  // duplicate idx_g: last (max g) wins (numpy sequential set)
    }
  }
  grid.sync();  // B

  // ================= P3: match + pos CE + hist0 + blockcnt =================
  if (b < L_SZ / NT) {
    int i = b * NT + tid;
    u64 rk = P.rowkey[i];
    float best = __uint_as_float((u32)(rk >> 32));
    int idxp = (int)(0xFFFFFFFFu - (u32)rk);
    int m;
    if (best < F_LOWER) m = -2;
    else {
      int s = P.scat[i];
      m = (s >= 0) ? s : ((best >= F_UPPER) ? idxp : -1);
    }
    P.matches[i] = m;
    u32 ub = threefry_bits((u32)i, L_SZ >> 1) >> 9;
    P.u23[i] = ub;
    if (m >= 0) {
      atomicAdd(&P.st->num_pos, 1);
      float ce = P.lse[i] - P.scores[(size_t)i * C_SZ + P.gtc[m]];
      atomicAdd(&P.st->sum_pos_ce, (double)ce);
    } else if (m == -2) {
      atomicAdd(&P.st->num_neg, 1);
      atomicAdd(&P.hist0[ub >> 10], 1u);  // (key>>26) == ub>>10
    }
    u64 bal = __ballot(m >= 0);
    int lane = tid & 63, wid = tid >> 6;
    if (lane == 0) swsum[wid] = __popcll(bal);
    __syncthreads();
    if (tid == 0) P.blockcnt[b] = swsum[0] + swsum[1] + swsum[2] + swsum[3];
  }
  grid.sync();  // C

  // ================= P4: ordered compaction + bin scan =================
  if (b < 256) {
    sscan[tid] = P.blockcnt[tid];
    __syncthreads();
    for (int off = 1; off < 256; off <<= 1) {
      int v = (tid >= off) ? sscan[tid - off] : 0;
      __syncthreads();
      sscan[tid] += v;
      __syncthreads();
    }
    int bpref = (b == 0) ? 0 : sscan[b - 1];
    if (bpref < MAX_POS) {  // uniform per block
      int i = b * NT + tid;
      int m = P.matches[i];
      int flag = (m >= 0) ? 1 : 0;
      int incl = flag;
      int lane = tid & 63, wid = tid >> 6;
#pragma unroll
      for (int off = 1; off < 64; off <<= 1) {
        int v = __shfl_up(incl, off, 64);
        if (lane >= off) incl += v;
      }
      if (lane == 63) swsum[wid] = incl;
      __syncthreads();
      int wbase = 0;
      for (int w = 0; w < wid; ++w) wbase += swsum[w];
      int rank = bpref + wbase + incl - flag;
      if (flag && rank < MAX_POS) { P.pp[rank] = P.pred[i]; P.gp[rank] = P.gtb[m]; }
    }
  } else if (b == 256) {
    int np = P.st->num_pos;  // bg_num = round(num_pos * 1.0)
    int nn = P.st->num_neg;
    if (np >= nn) {
      if (tid == 0) P.st->select_all = 1;
    } else {
      int loc[32]; int tsum = 0;
#pragma unroll
      for (int r = 0; r < 32; ++r) { loc[r] = (int)P.hist0[tid * 32 + r]; tsum += loc[r]; }
      sscan[tid] = tsum;
      __syncthreads();
      for (int off = 1; off < 256; off <<= 1) {
        int v = (tid >= off) ? sscan[tid - off] : 0;
        __syncthreads();
        sscan[tid] += v;
        __syncthreads();
      }
      int incl = sscan[tid], excl = incl - tsum;
      if (np >= excl && np < incl) {
        int kk = np - excl; int d = 0;
#pragma unroll
        for (int r = 0; r < 32; ++r) {
          if (kk < loc[r]) { d = tid * 32 + r; break; }
          kk -= loc[r];
        }
        P.st->prefix = (u64)d;
        P.st->sel_k = kk;
      }
    }
  }
  grid.sync();  // D

  // ================= P5: collect boundary-bin candidates + pair loss =================
  if (b < 256) {
    if (!P.st->select_all) {
      u32 b0 = (u32)P.st->prefix;
      int i = b * NT + tid;
      if (P.matches[i] == -2) {
        u32 ub = P.u23[i];
        if ((ub >> 10) == b0) {
          u32 pos = atomicAdd(&P.st->cand_cnt, 1u);
          if (pos < CAND_CAP) P.cand[pos] = ((u64)ub << 16) | (u32)i;
        }
      }
    }
  } else if (b < 256 + 128) {
    int q = b - 256;
    int n = P.st->num_pos; if (n > MAX_POS) n = MAX_POS;
    int jb = (q >> 3) * 128;
    if (tid < 128) {
      int j = jb + tid;
      sg[tid] = (j < n) ? P.pp[j] : make_float4(0.f, 0.f, 0.f, 0.f);
    }
    __syncthreads();
    int i = (q & 7) * NT + tid;
    double acc = 0.0;
    if (i < n) {
      float4 g = P.gp[i];
      int jend = n - jb; if (jend > 128) jend = 128;
      for (int j = 0; j < jend; ++j) {
        float4 p4 = sg[j];
        acc += (double)sl1(p4.x - g.x);
        acc += (double)sl1(p4.y - g.y);
        acc += (double)sl1(p4.z - g.z);
        acc += (double)sl1(p4.w - g.w);
      }
    }
    for (int off = 32; off > 0; off >>= 1) acc += __shfl_down(acc, off, 64);
    int lane = tid & 63, wid = tid >> 6;
    if (lane == 0) sdacc[wid] = acc;
    __syncthreads();
    if (tid == 0) atomicAdd(&P.st->bbox_sum, sdacc[0] + sdacc[1] + sdacc[2] + sdacc[3]);
  }
  grid.sync();  // E

  // ================= P6: negative CE with in-block rank-select threshold =================
  if (b < 256) {
    int sel_all = P.st->select_all;
    u64 thresh = ~0ull;
    if (!sel_all) {
      u32 cnt = P.st->cand_cnt; if (cnt > CAND_CAP) cnt = CAND_CAP;
      int kk = P.st->sel_k;
      u64* scand = (u64*)sg;  // reuse (8KB = 1024 u64)
      for (int t = tid; t < (int)cnt; t += NT) scand[t] = P.cand[t];
      __syncthreads();
      for (int t = tid; t < (int)cnt; t += NT) {
        u64 key = scand[t];
        int rank = 0;
        for (int u = 0; u < (int)cnt; ++u) rank += (scand[u] < key) ? 1 : 0;
        if (rank == kk) sth = key;  // unique keys -> single writer
      }
      __syncthreads();
      thresh = sth;
    }
    int i = b * NT + tid;
    double acc = 0.0;
    if (P.matches[i] == -2) {
      u64 key = ((u64)P.u23[i] << 16) | (u32)i;
      if (key < thresh)
        acc = (double)(P.lse[i] - P.scores[(size_t)i * C_SZ + (C_SZ - 1)]);  // BACKGROUND=20
    }
    for (int off = 32; off > 0; off >>= 1) acc += __shfl_down(acc, off, 64);
    int lane = tid & 63, wid = tid >> 6;
    if (lane == 0) sdacc[wid] = acc;
    __syncthreads();
    if (tid == 0) atomicAdd(&P.st->sum_neg_ce, sdacc[0] + sdacc[1] + sdacc[2] + sdacc[3]);
  }
  grid.sync();  // F

  // ================= P7: final =================
  if (b == 0 && tid == 0) {
    int np = P.st->num_pos, nn = P.st->num_neg;
    int nsel = (np < nn) ? np : nn;
    double wsum = (double)(np + nsel);
    P.out[0] = (float)((P.st->sum_pos_ce + P.st->sum_neg_ce) / wsum);
    P.out[1] = (float)P.st->bbox_sum;
  }
}

// ---------- launch ----------

extern "C" void kernel_launch(void* const* d_in, const int* in_sizes, int n_in,
                              void* d_out, int out_size, void* d_ws, size_t ws_size,
                              hipStream_t stream) {
  Params P;
  P.rois   = (const float*)d_in[0];
  P.scores = (const float*)d_in[1];
  P.deltas = (const float*)d_in[2];
  P.gtb    = (const float4*)d_in[3];
  P.gtc    = (const int*)d_in[4];
  P.out    = (float*)d_out;

  char* w = (char*)d_ws;
  // zero-init region: State | gkey | hist0 (one memset)
  P.st     = (State*)w;       w += 256;
  P.gkey   = (u64*)w;         w += (size_t)M_SZ * 8;
  P.hist0  = (u32*)w;         w += (size_t)NBINS * 4;
  char* zero_end = w;
  // 0xFF-init region: scat (= -1 ints)
  P.scat   = (int*)w;         w += (size_t)L_SZ * 4;
  // no-init scratch
  P.pred   = (float4*)w;      w += (size_t)L_SZ * 16;
  P.lse    = (float*)w;       w += (size_t)L_SZ * 4;
  P.rowkey = (u64*)w;         w += (size_t)L_SZ * 8;
  P.matches= (int*)w;         w += (size_t)L_SZ * 4;
  P.u23    = (u32*)w;         w += (size_t)L_SZ * 4;
  P.blockcnt = (int*)w;       w += 256 * 4;
  P.pp     = (float4*)w;      w += (size_t)MAX_POS * 16;
  P.gp     = (float4*)w;      w += (size_t)MAX_POS * 16;
  P.cand   = (u64*)w;         w += (size_t)CAND_CAP * 8;

  hipMemsetAsync(d_ws, 0, (size_t)(zero_end - (char*)d_ws), stream);
  hipMemsetAsync(P.scat, 0xFF, (size_t)L_SZ * 4, stream);

  void* args[] = { &P };
  hipLaunchCooperativeKernel((void*)mega, dim3(NB), dim3(NT), args, 0, stream);
}

// Round 4
// 331.509 us; speedup vs baseline: 1.3247x; 1.3247x over previous
//
#include <hip/hip_runtime.h>
#include <hip/hip_cooperative_groups.h>
#include <stdint.h>

namespace cg = cooperative_groups;

typedef unsigned int u32;
typedef unsigned long long u64;

#define F_UPPER 0.4f
#define F_LOWER 0.1f
#define MAX_POS 2048
#define NB 512
#define NT 256
#define L_SZ 65536
#define M_SZ 512
#define C_SZ 21
#define NBINS 8192
#define CAND_CAP 1024

struct State {
  double sum_pos_ce;
  double sum_neg_ce;
  double bbox_sum;
  int num_pos;
  int num_neg;
  u32 cand_cnt;
  u32 _pad;
};

struct Params {
  const float* rois; const float* scores; const float* deltas;
  const float4* gtb; const int* gtc; float* out;
  State* st; u64* gkey; u32* hist0;
  float4* pred; float* lse; u64* rowkey;
  int* blockcnt; float4* pp; float4* gp; u64* cand;
};

__device__ __forceinline__ float area_fn(const float4 a) {
#pragma clang fp contract(off)
  return (a.z - a.x + 1.0f) * (a.w - a.y + 1.0f);
}

__device__ __forceinline__ float sl1(float d) {
#pragma clang fp contract(off)
  float ad = fabsf(d);
  return (ad < 0.01f) ? (50.0f * d * d) : (ad - 0.005f);
}

__device__ __forceinline__ u32 rotl(u32 x, int d) { return (x << d) | (x >> (32 - d)); }

// JAX threefry2x32, key=(0,42); counts = iota(L) split in halves.
__device__ u32 threefry_bits(u32 i, u32 H) {
  u32 x0, x1; bool hi;
  if (i < H) { x0 = i;     x1 = i + H; hi = false; }
  else       { x0 = i - H; x1 = i;     hi = true;  }
  const u32 ks0 = 0u, ks1 = 42u;
  const u32 ks2 = ks0 ^ ks1 ^ 0x1BD11BDAu;
  x0 += ks0; x1 += ks1;
#define RND(r) { x0 += x1; x1 = rotl(x1, r); x1 ^= x0; }
  RND(13) RND(15) RND(26) RND(6)   x0 += ks1; x1 += ks2 + 1u;
  RND(17) RND(29) RND(16) RND(24)  x0 += ks2; x1 += ks0 + 2u;
  RND(13) RND(15) RND(26) RND(6)   x0 += ks0; x1 += ks1 + 3u;
  RND(17) RND(29) RND(16) RND(24)  x0 += ks1; x1 += ks2 + 4u;
  RND(13) RND(15) RND(26) RND(6)   x0 += ks2; x1 += ks0 + 5u;
#undef RND
  return hi ? x1 : x0;
}

__global__ void __launch_bounds__(NT, 2) mega(Params P) {
  cg::grid_group grid = cg::this_grid();
  const int tid = threadIdx.x;
  const int b = blockIdx.x;
  const int lane = tid & 63;
  const int wid = tid >> 6;

  __shared__ float4 sg[M_SZ];        // gt boxes; reused as pairs j-tile in P5
  __shared__ float  ga[M_SZ];
  __shared__ float4 spred[128];
  __shared__ float  sarea[128];
  __shared__ float  ssc[128 * C_SZ];
  __shared__ float  sro[128 * 5];
  __shared__ u64    srow[NT];
  __shared__ int    sscan[NT];
  __shared__ int    sscat[NT];
  __shared__ int    swsum[4];
  __shared__ double sdacc[4];
  __shared__ int    s_d, s_kk;
  __shared__ u64    sth;
  __shared__ u64    scand[CAND_CAP];

  // ============ P1: ROI + IoU (two-phase, register max, no inner-loop atomics) ============
  {
    const int pbase = b << 7;
    for (int k = tid; k < 128 * C_SZ; k += NT) ssc[k] = P.scores[(size_t)pbase * C_SZ + k];
    for (int k = tid; k < 128 * 5; k += NT)    sro[k] = P.rois[(size_t)pbase * 5 + k];
    for (int j = tid; j < M_SZ; j += NT) {
      float4 g = P.gtb[j];
      sg[j] = g; ga[j] = area_fn(g);
    }
    __syncthreads();
    if (tid < 128) {
      const int i = pbase + tid;
      const float* sr = ssc + tid * C_SZ;
      float mx = sr[0]; int mi = 0;
      for (int j = 1; j < C_SZ; ++j) { float v = sr[j]; if (v > mx) { mx = v; mi = j; } }
      float s = 0.0f;
      for (int j = 0; j < C_SZ; ++j) s += expf(sr[j] - mx);
      P.lse[i] = mx + logf(s);
      // 16B-aligned gather: (84*i + 4*mi) floats is a multiple of 4 floats.
      float4 d = *(const float4*)(P.deltas + (size_t)i * (4 * C_SZ) + 4 * mi);
      const float* r = sro + tid * 5;
      float4 pb;
      pb.x = r[1] + d.x; pb.y = r[2] + d.y; pb.z = r[3] + d.z; pb.w = r[4] + d.w;
      spred[tid] = pb; sarea[tid] = area_fn(pb);
      P.pred[i] = pb;
    }
    __syncthreads();
    // Row phase: 2 threads per pred, 256 gts each; first-max tie-break (ascending j).
    {
      const int p = tid & 127;
      const int j0 = (tid >> 7) << 8;
      const float4 pb = spred[p];
      const float pa = sarea[p];
      float rbest = -1.0f; int rbj = 0;
#pragma unroll 4
      for (int jj = 0; jj < 256; ++jj) {
#pragma clang fp contract(off)
        int j = j0 + jj;
        float4 gb = sg[j];
        float iw = fminf(pb.z, gb.z) - fmaxf(pb.x, gb.x) + 1.0f;
        iw = fmaxf(iw, 0.0f);
        float ih = fminf(pb.w, gb.w) - fmaxf(pb.y, gb.y) + 1.0f;
        ih = fmaxf(ih, 0.0f);
        float inter = iw * ih;
        float v = inter * __builtin_amdgcn_rcpf(pa + ga[j] - inter);
        if (v > rbest) { rbest = v; rbj = j; }
      }
      srow[tid] = ((u64)__float_as_uint(rbest) << 32) | (u32)(0xFFFFFFFFu - (u32)rbj);
    }
    __syncthreads();
    if (tid < 128) {
      u64 a = srow[tid], c = srow[tid + 128];
      P.rowkey[pbase + tid] = (a > c) ? a : c;  // equal-float tie -> smaller j (larger low32)
    }
    // Col phase: 2 gts/thread over this block's 128 preds; merge across blocks via atomicMax.
    for (int j = tid; j < M_SZ; j += NT) {
      const float4 gb = sg[j];
      const float gba = ga[j];
      float cbest = -1.0f; int cbp = 0;
#pragma unroll 4
      for (int p2 = 0; p2 < 128; ++p2) {
#pragma clang fp contract(off)
        float4 pb = spred[p2];
        float iw = fminf(pb.z, gb.z) - fmaxf(pb.x, gb.x) + 1.0f;
        iw = fmaxf(iw, 0.0f);
        float ih = fminf(pb.w, gb.w) - fmaxf(pb.y, gb.y) + 1.0f;
        ih = fmaxf(ih, 0.0f);
        float inter = iw * ih;
        float v = inter * __builtin_amdgcn_rcpf(sarea[p2] + gba - inter);
        if (v > cbest) { cbest = v; cbp = p2; }
      }
      u64 key = ((u64)__float_as_uint(cbest) << 32) | (u32)(0xFFFFFFFFu - (u32)(pbase + cbp));
      atomicMax(&P.gkey[j], key);
    }
  }
  grid.sync();  // A

  // Persisted per-thread state for i = b*256 + tid (blocks b < 256).
  int m_reg = -1;
  u32 ub = 0;
  u64 nkey = 0;

  // ============ P2: scat-from-gkey (in LDS) + match + pos CE + hist0 + counts ============
  if (b < 256) {
    sscat[tid] = -1;
    __syncthreads();
    for (int g = tid; g < M_SZ; g += NT) {
      u64 key = P.gkey[g];
      int pidx = (int)(0xFFFFFFFFu - (u32)key);
      if ((pidx >> 8) == b) atomicMax(&sscat[pidx & 255], g);  // dup idx_g: max g wins
    }
    __syncthreads();
    const int i = (b << 8) + tid;
    u64 rk = P.rowkey[i];
    float best = __uint_as_float((u32)(rk >> 32));
    int idxp = (int)(0xFFFFFFFFu - (u32)rk);
    if (best < F_LOWER) m_reg = -2;
    else {
      int s = sscat[tid];
      m_reg = (s >= 0) ? s : ((best >= F_UPPER) ? idxp : -1);
    }
    ub = threefry_bits((u32)i, L_SZ >> 1) >> 9;
    nkey = ((u64)ub << 16) | (u32)i;
    float ce = 0.0f;
    if (m_reg >= 0) ce = P.lse[i] - P.scores[(size_t)i * C_SZ + P.gtc[m_reg]];
    else if (m_reg == -2) atomicAdd(&P.hist0[ub >> 10], 1u);
    u64 balp = __ballot(m_reg >= 0);
    u64 baln = __ballot(m_reg == -2);
    double acc = (double)ce;
    for (int off = 32; off > 0; off >>= 1) acc += __shfl_down(acc, off, 64);
    if (lane == 0) { swsum[wid] = __popcll(balp); sscan[wid] = __popcll(baln); sdacc[wid] = acc; }
    __syncthreads();
    if (tid == 0) {
      int cp = swsum[0] + swsum[1] + swsum[2] + swsum[3];
      int cn = sscan[0] + sscan[1] + sscan[2] + sscan[3];
      P.blockcnt[b] = cp;
      atomicAdd(&P.st->num_pos, cp);
      atomicAdd(&P.st->num_neg, cn);
      atomicAdd(&P.st->sum_pos_ce, sdacc[0] + sdacc[1] + sdacc[2] + sdacc[3]);
    }
  }
  grid.sync();  // B

  // ============ P3: ordered compaction + redundant bin-scan + cand collect ============
  if (b < 256) {
    sscan[tid] = P.blockcnt[tid];
    __syncthreads();
    for (int off = 1; off < 256; off <<= 1) {
      int v = (tid >= off) ? sscan[tid - off] : 0;
      __syncthreads();
      sscan[tid] += v;
      __syncthreads();
    }
    int bpref = (b == 0) ? 0 : sscan[b - 1];
    if (bpref < MAX_POS) {  // block-uniform
      int flag = (m_reg >= 0) ? 1 : 0;
      int incl = flag;
#pragma unroll
      for (int off = 1; off < 64; off <<= 1) {
        int v = __shfl_up(incl, off, 64);
        if (lane >= off) incl += v;
      }
      if (lane == 63) swsum[wid] = incl;
      __syncthreads();
      int wbase = 0;
      for (int w = 0; w < wid; ++w) wbase += swsum[w];
      int rank = bpref + wbase + incl - flag;
      if (flag && rank < MAX_POS) {
        const int i = (b << 8) + tid;
        P.pp[rank] = P.pred[i];
        P.gp[rank] = P.gtb[m_reg];
      }
    }
    __syncthreads();
    // Redundant bin-scan: every block derives (d, kk) locally. bg_num = num_pos.
    int np = P.st->num_pos, nn = P.st->num_neg;
    if (np < nn) {
      int loc[32]; int tsum = 0;
#pragma unroll
      for (int r = 0; r < 32; ++r) { loc[r] = (int)P.hist0[tid * 32 + r]; tsum += loc[r]; }
      sscan[tid] = tsum;
      __syncthreads();
      for (int off = 1; off < 256; off <<= 1) {
        int v = (tid >= off) ? sscan[tid - off] : 0;
        __syncthreads();
        sscan[tid] += v;
        __syncthreads();
      }
      int incl = sscan[tid], excl = incl - tsum;
      if (np >= excl && np < incl) {
        int kk = np - excl; int d = 0;
#pragma unroll
        for (int r = 0; r < 32; ++r) {
          if (kk < loc[r]) { d = tid * 32 + r; break; }
          kk -= loc[r];
        }
        s_d = d; s_kk = kk;
      }
      __syncthreads();
      // Collect boundary-bin candidates from own range.
      if (m_reg == -2 && (int)(ub >> 10) == s_d) {
        u32 pos = atomicAdd(&P.st->cand_cnt, 1u);
        if (pos < CAND_CAP) P.cand[pos] = nkey;
      }
    }
  }
  grid.sync();  // C

  // ============ P4: negative CE (rank-select threshold) + pair loss ============
  if (b < 256) {
    int np = P.st->num_pos, nn = P.st->num_neg;
    u64 thresh = ~0ull;  // np >= nn -> all negatives selected
    if (np < nn) {
      u32 cnt = P.st->cand_cnt; if (cnt > CAND_CAP) cnt = CAND_CAP;
      for (int t = tid; t < (int)cnt; t += NT) scand[t] = P.cand[t];
      __syncthreads();
      int kk = s_kk;  // persisted in LDS from P3
      for (int t = tid; t < (int)cnt; t += NT) {
        u64 key = scand[t];
        int rank = 0;
        for (int u = 0; u < (int)cnt; ++u) rank += (scand[u] < key) ? 1 : 0;
        if (rank == kk) sth = key;  // keys unique -> single writer
      }
      __syncthreads();
      thresh = sth;
    }
    double acc = 0.0;
    if (m_reg == -2 && nkey < thresh) {
      const int i = (b << 8) + tid;
      acc = (double)(P.lse[i] - P.scores[(size_t)i * C_SZ + (C_SZ - 1)]);  // BACKGROUND=20
    }
    for (int off = 32; off > 0; off >>= 1) acc += __shfl_down(acc, off, 64);
    if (lane == 0) sdacc[wid] = acc;
    __syncthreads();
    if (tid == 0) atomicAdd(&P.st->sum_neg_ce, sdacc[0] + sdacc[1] + sdacc[2] + sdacc[3]);
  } else if (b < 256 + 128) {
    int q = b - 256;
    int n = P.st->num_pos; if (n > MAX_POS) n = MAX_POS;
    int jb = (q >> 3) * 128;
    if (tid < 128) {
      int j = jb + tid;
      sg[tid] = (j < n) ? P.pp[j] : make_float4(0.f, 0.f, 0.f, 0.f);
    }
    __syncthreads();
    int i = (q & 7) * NT + tid;
    double acc = 0.0;
    if (i < n) {
      float4 g = P.gp[i];
      int jend = n - jb; if (jend > 128) jend = 128;
      for (int j = 0; j < jend; ++j) {
        float4 p4 = sg[j];
        acc += (double)sl1(p4.x - g.x);
        acc += (double)sl1(p4.y - g.y);
        acc += (double)sl1(p4.z - g.z);
        acc += (double)sl1(p4.w - g.w);
      }
    }
    for (int off = 32; off > 0; off >>= 1) acc += __shfl_down(acc, off, 64);
    if (lane == 0) sdacc[wid] = acc;
    __syncthreads();
    if (tid == 0) atomicAdd(&P.st->bbox_sum, sdacc[0] + sdacc[1] + sdacc[2] + sdacc[3]);
  }
  grid.sync();  // D

  // ============ P5: final ============
  if (b == 0 && tid == 0) {
    int np = P.st->num_pos, nn = P.st->num_neg;
    int nsel = (np < nn) ? np : nn;
    double wsum = (double)(np + nsel);
    P.out[0] = (float)((P.st->sum_pos_ce + P.st->sum_neg_ce) / wsum);
    P.out[1] = (float)P.st->bbox_sum;
  }
}

// ---------- launch ----------

extern "C" void kernel_launch(void* const* d_in, const int* in_sizes, int n_in,
                              void* d_out, int out_size, void* d_ws, size_t ws_size,
                              hipStream_t stream) {
  Params P;
  P.rois   = (const float*)d_in[0];
  P.scores = (const float*)d_in[1];
  P.deltas = (const float*)d_in[2];
  P.gtb    = (const float4*)d_in[3];
  P.gtc    = (const int*)d_in[4];
  P.out    = (float*)d_out;

  char* w = (char*)d_ws;
  // zero-init region: State | gkey | hist0 (single small memset, ~37KB)
  P.st     = (State*)w;       w += 256;
  P.gkey   = (u64*)w;         w += (size_t)M_SZ * 8;
  P.hist0  = (u32*)w;         w += (size_t)NBINS * 4;
  char* zero_end = w;
  // no-init scratch
  P.pred   = (float4*)w;      w += (size_t)L_SZ * 16;
  P.lse    = (float*)w;       w += (size_t)L_SZ * 4;
  P.rowkey = (u64*)w;         w += (size_t)L_SZ * 8;
  P.blockcnt = (int*)w;       w += 256 * 4;
  P.pp     = (float4*)w;      w += (size_t)MAX_POS * 16;
  P.gp     = (float4*)w;      w += (size_t)MAX_POS * 16;
  P.cand   = (u64*)w;         w += (size_t)CAND_CAP * 8;

  hipMemsetAsync(d_ws, 0, (size_t)(zero_end - (char*)d_ws), stream);

  void* args[] = { &P };
  hipLaunchCooperativeKernel((void*)mega, dim3(NB), dim3(NT), args, 0, stream);
}

// Round 5
// 234.949 us; speedup vs baseline: 1.8692x; 1.4110x over previous
//
#include <hip/hip_runtime.h>
#include <stdint.h>

typedef unsigned int u32;
typedef unsigned long long u64;

#define F_UPPER 0.4f
#define F_LOWER 0.1f
#define MAX_POS 2048
#define L_SZ 65536
#define M_SZ 512
#define C_SZ 21
#define NBINS 8192
#define CAND_CAP 1024

struct State {
  double sum_pos_ce;
  double sum_neg_ce;
  double bbox_sum;
  int num_pos;
  int num_neg;
  u32 done;
  u32 _pad;
};

__device__ __forceinline__ float area_fn(const float4 a) {
#pragma clang fp contract(off)
  return (a.z - a.x + 1.0f) * (a.w - a.y + 1.0f);
}

__device__ __forceinline__ float sl1(float d) {
#pragma clang fp contract(off)
  float ad = fabsf(d);
  return (ad < 0.01f) ? (50.0f * d * d) : (ad - 0.005f);
}

__device__ __forceinline__ u32 rotl(u32 x, int d) { return (x << d) | (x >> (32 - d)); }

// JAX threefry2x32, key=(0,42); counts = iota(L) split in halves.
__device__ u32 threefry_bits(u32 i, u32 H) {
  u32 x0, x1; bool hi;
  if (i < H) { x0 = i;     x1 = i + H; hi = false; }
  else       { x0 = i - H; x1 = i;     hi = true;  }
  const u32 ks0 = 0u, ks1 = 42u;
  const u32 ks2 = ks0 ^ ks1 ^ 0x1BD11BDAu;
  x0 += ks0; x1 += ks1;
#define RND(r) { x0 += x1; x1 = rotl(x1, r); x1 ^= x0; }
  RND(13) RND(15) RND(26) RND(6)   x0 += ks1; x1 += ks2 + 1u;
  RND(17) RND(29) RND(16) RND(24)  x0 += ks2; x1 += ks0 + 2u;
  RND(13) RND(15) RND(26) RND(6)   x0 += ks0; x1 += ks1 + 3u;
  RND(17) RND(29) RND(16) RND(24)  x0 += ks1; x1 += ks2 + 4u;
  RND(13) RND(15) RND(26) RND(6)   x0 += ks2; x1 += ks0 + 5u;
#undef RND
  return hi ? x1 : x0;
}

// ======== k1: ROI (argmax/lse/pred) + IoU row/col maxes. 1024 blocks x 64 preds x 512 gts.
__global__ void __launch_bounds__(256) k1(const float* __restrict__ rois,
    const float* __restrict__ scores, const float* __restrict__ deltas,
    const float4* __restrict__ gtb,
    float4* __restrict__ pred, float* __restrict__ lse,
    u64* __restrict__ rowkey, u64* __restrict__ gkey) {
  __shared__ float  ssc[64 * C_SZ];
  __shared__ float  sro[64 * 5];
  __shared__ float4 sg[M_SZ];
  __shared__ float  ga[M_SZ];
  __shared__ float4 spred[64];
  __shared__ float  sarea[64];
  __shared__ u64    srow[256];
  const int tid = threadIdx.x;
  const int pbase = blockIdx.x << 6;
  for (int k = tid; k < 64 * C_SZ; k += 256) ssc[k] = scores[(size_t)pbase * C_SZ + k];
  for (int k = tid; k < 64 * 5; k += 256)    sro[k] = rois[(size_t)pbase * 5 + k];
  for (int j = tid; j < M_SZ; j += 256) { float4 g = gtb[j]; sg[j] = g; ga[j] = area_fn(g); }
  __syncthreads();
  if (tid < 64) {
    const int i = pbase + tid;
    const float* sr = ssc + tid * C_SZ;
    float mx = sr[0]; int mi = 0;
    for (int j = 1; j < C_SZ; ++j) { float v = sr[j]; if (v > mx) { mx = v; mi = j; } }
    float s = 0.0f;
    for (int j = 0; j < C_SZ; ++j) s += expf(sr[j] - mx);
    lse[i] = mx + logf(s);
    // 16B-aligned gather: (84*i + 4*mi) floats is a multiple of 4 floats.
    float4 d = *(const float4*)(deltas + (size_t)i * (4 * C_SZ) + 4 * mi);
    const float* r = sro + tid * 5;
    float4 pb;
    pb.x = r[1] + d.x; pb.y = r[2] + d.y; pb.z = r[3] + d.z; pb.w = r[4] + d.w;
    spred[tid] = pb; sarea[tid] = area_fn(pb);
    pred[i] = pb;
  }
  __syncthreads();
  // Row phase: 4 threads per pred, 128 gts each (ascending j -> first-max tie-break).
  {
    const int p = tid & 63;
    const int j0 = (tid >> 6) << 7;
    const float4 pb = spred[p];
    const float pa = sarea[p];
    float rbest = -1.0f; int rbj = 0;
#pragma unroll 4
    for (int jj = 0; jj < 128; ++jj) {
#pragma clang fp contract(off)
      int j = j0 + jj;
      float4 gb = sg[j];
      float iw = fminf(pb.z, gb.z) - fmaxf(pb.x, gb.x) + 1.0f;
      iw = fmaxf(iw, 0.0f);
      float ih = fminf(pb.w, gb.w) - fmaxf(pb.y, gb.y) + 1.0f;
      ih = fmaxf(ih, 0.0f);
      float inter = iw * ih;
      float v = inter * __builtin_amdgcn_rcpf(pa + ga[j] - inter);
      if (v > rbest) { rbest = v; rbj = j; }
    }
    srow[tid] = ((u64)__float_as_uint(rbest) << 32) | (u32)(0xFFFFFFFFu - (u32)rbj);
  }
  __syncthreads();
  if (tid < 64) {
    u64 a = srow[tid], c = srow[tid + 64];
    u64 d = srow[tid + 128], e = srow[tid + 192];
    if (c > a) a = c;
    if (e > d) d = e;
    if (d > a) a = d;  // equal-float tie -> larger low32 = smaller j (first max)
    rowkey[pbase + tid] = a;
  }
  // Col phase: 2 gts/thread over this block's 64 preds; cross-block merge via atomicMax.
  for (int g = tid; g < M_SZ; g += 256) {
    const float4 gb = sg[g];
    const float gba = ga[g];
    float cbest = -1.0f; int cbp = 0;
#pragma unroll 4
    for (int p2 = 0; p2 < 64; ++p2) {
#pragma clang fp contract(off)
      float4 pb = spred[p2];
      float iw = fminf(pb.z, gb.z) - fmaxf(pb.x, gb.x) + 1.0f;
      iw = fmaxf(iw, 0.0f);
      float ih = fminf(pb.w, gb.w) - fmaxf(pb.y, gb.y) + 1.0f;
      ih = fmaxf(ih, 0.0f);
      float inter = iw * ih;
      float v = inter * __builtin_amdgcn_rcpf(sarea[p2] + gba - inter);
      if (v > cbest) { cbest = v; cbp = p2; }
    }
    u64 key = ((u64)__float_as_uint(cbest) << 32) | (u32)(0xFFFFFFFFu - (u32)(pbase + cbp));
    atomicMax(&gkey[g], key);
  }
}

// ======== k2: scat + match + pos CE + hist0 + blockcnt + matches/neg_u. 256 blocks.
__global__ void __launch_bounds__(256) k2(const u64* __restrict__ rowkey,
    const u64* __restrict__ gkey, const int* __restrict__ gtc,
    const float* __restrict__ scores, const float* __restrict__ lse,
    int* __restrict__ matches, u32* __restrict__ neg_u,
    int* __restrict__ blockcnt, u32* __restrict__ hist0, State* st) {
  __shared__ int sscat[256];
  __shared__ int swsum[4], sncnt[4];
  __shared__ double sdacc[4];
  const int tid = threadIdx.x;
  const int b = blockIdx.x;
  const int lane = tid & 63, wid = tid >> 6;
  sscat[tid] = -1;
  __syncthreads();
  for (int g = tid; g < M_SZ; g += 256) {
    u64 key = gkey[g];
    int pidx = (int)(0xFFFFFFFFu - (u32)key);
    if ((pidx >> 8) == b) atomicMax(&sscat[pidx & 255], g);  // dup idx_g: last (max g) wins
  }
  __syncthreads();
  const int i = (b << 8) + tid;
  u64 rk = rowkey[i];
  float best = __uint_as_float((u32)(rk >> 32));
  int idxp = (int)(0xFFFFFFFFu - (u32)rk);
  int m;
  if (best < F_LOWER) m = -2;
  else {
    int s = sscat[tid];
    m = (s >= 0) ? s : ((best >= F_UPPER) ? idxp : -1);
  }
  matches[i] = m;
  u32 ub = threefry_bits((u32)i, L_SZ >> 1) >> 9;
  neg_u[i] = (m == -2) ? ub : 0xFFFFFFFFu;
  float ce = 0.0f;
  if (m >= 0) ce = lse[i] - scores[(size_t)i * C_SZ + gtc[m]];
  else if (m == -2) atomicAdd(&hist0[ub >> 10], 1u);
  u64 balp = __ballot(m >= 0);
  u64 baln = __ballot(m == -2);
  double acc = (double)ce;
  for (int off = 32; off > 0; off >>= 1) acc += __shfl_down(acc, off, 64);
  if (lane == 0) { swsum[wid] = __popcll(balp); sncnt[wid] = __popcll(baln); sdacc[wid] = acc; }
  __syncthreads();
  if (tid == 0) {
    int cp = swsum[0] + swsum[1] + swsum[2] + swsum[3];
    int cn = sncnt[0] + sncnt[1] + sncnt[2] + sncnt[3];
    blockcnt[b] = cp;
    atomicAdd(&st->num_pos, cp);
    atomicAdd(&st->num_neg, cn);
    atomicAdd(&st->sum_pos_ce, sdacc[0] + sdacc[1] + sdacc[2] + sdacc[3]);
  }
}

// ======== k3: index-ordered compaction of first MAX_POS positives. 256 blocks.
__global__ void __launch_bounds__(256) k3(const int* __restrict__ matches,
    const float4* __restrict__ pred, const float4* __restrict__ gtb,
    const int* __restrict__ blockcnt, float4* __restrict__ pp, float4* __restrict__ gp) {
  __shared__ int sscan[256];
  __shared__ int swsum[4];
  const int tid = threadIdx.x, b = blockIdx.x;
  const int lane = tid & 63, wid = tid >> 6;
  sscan[tid] = blockcnt[tid];
  __syncthreads();
  for (int off = 1; off < 256; off <<= 1) {
    int v = (tid >= off) ? sscan[tid - off] : 0;
    __syncthreads();
    sscan[tid] += v;
    __syncthreads();
  }
  int bpref = (b == 0) ? 0 : sscan[b - 1];
  if (bpref >= MAX_POS) return;  // block-uniform
  const int i = (b << 8) + tid;
  int m = matches[i];
  int flag = (m >= 0) ? 1 : 0;
  int incl = flag;
#pragma unroll
  for (int off = 1; off < 64; off <<= 1) {
    int v = __shfl_up(incl, off, 64);
    if (lane >= off) incl += v;
  }
  if (lane == 63) swsum[wid] = incl;
  __syncthreads();
  int wbase = 0;
  for (int w = 0; w < wid; ++w) wbase += swsum[w];
  int rank = bpref + wbase + incl - flag;
  if (flag && rank < MAX_POS) { pp[rank] = pred[i]; gp[rank] = gtb[m]; }
}

// ======== k4: neg selection (redundant bin-scan + cand sweep + rank-select) + neg CE.
__global__ void __launch_bounds__(256) k4(const u32* __restrict__ neg_u,
    const u32* __restrict__ hist0, const float* __restrict__ scores,
    const float* __restrict__ lse, State* st) {
  __shared__ int sscan[256];
  __shared__ int s_d, s_kk;
  __shared__ u32 scnt;
  __shared__ u64 scand[CAND_CAP];
  __shared__ u64 sth;
  __shared__ double sdacc[4];
  const int tid = threadIdx.x, b = blockIdx.x;
  const int lane = tid & 63, wid = tid >> 6;
  const int np = st->num_pos, nn = st->num_neg;  // bg_num = round(np*1.0) = np
  u64 thresh = ~0ull;
  if (np < nn) {
    if (tid == 0) scnt = 0;
    // bin scan over hist0 (vectorized loads)
    const uint4* h4 = (const uint4*)hist0;
    u32 loc[32]; int tsum = 0;
#pragma unroll
    for (int r = 0; r < 8; ++r) {
      uint4 v = h4[tid * 8 + r];
      loc[r*4] = v.x; loc[r*4+1] = v.y; loc[r*4+2] = v.z; loc[r*4+3] = v.w;
      tsum += v.x + v.y + v.z + v.w;
    }
    sscan[tid] = tsum;
    __syncthreads();
    for (int off = 1; off < 256; off <<= 1) {
      int v = (tid >= off) ? sscan[tid - off] : 0;
      __syncthreads();
      sscan[tid] += v;
      __syncthreads();
    }
    int incl = sscan[tid], excl = incl - tsum;
    if (np >= excl && np < incl) {
      int kk = np - excl; int d = 0;
#pragma unroll
      for (int r = 0; r < 32; ++r) {
        if (kk < (int)loc[r]) { d = tid * 32 + r; break; }
        kk -= (int)loc[r];
      }
      s_d = d; s_kk = kk;
    }
    __syncthreads();
    const u32 d = (u32)s_d;
    // sweep all negatives for boundary-bin candidates (neg_u is L2-resident, 256KB)
    for (int t = tid; t < L_SZ; t += 256) {
      u32 u = neg_u[t];
      if (u != 0xFFFFFFFFu && (u >> 10) == d) {
        u32 pos = atomicAdd(&scnt, 1u);
        if (pos < CAND_CAP) scand[pos] = ((u64)u << 16) | (u32)t;
      }
    }
    __syncthreads();
    int cnt = (int)scnt; if (cnt > CAND_CAP) cnt = CAND_CAP;
    int kk = s_kk;
    for (int t = tid; t < cnt; t += 256) {
      u64 key = scand[t];
      int rank = 0;
      for (int u = 0; u < cnt; ++u) rank += (scand[u] < key) ? 1 : 0;
      if (rank == kk) sth = key;  // keys unique -> single writer
    }
    __syncthreads();
    thresh = sth;
  }
  const int i = (b << 8) + tid;
  u32 u = neg_u[i];
  double acc = 0.0;
  if (u != 0xFFFFFFFFu) {
    u64 key = ((u64)u << 16) | (u32)i;
    if (key < thresh)
      acc = (double)(lse[i] - scores[(size_t)i * C_SZ + (C_SZ - 1)]);  // BACKGROUND=20
  }
  for (int off = 32; off > 0; off >>= 1) acc += __shfl_down(acc, off, 64);
  if (lane == 0) sdacc[wid] = acc;
  __syncthreads();
  if (tid == 0) atomicAdd(&st->sum_neg_ce, sdacc[0] + sdacc[1] + sdacc[2] + sdacc[3]);
}

// ======== k5: pair smooth-L1 loss + last-block final write. grid (8,16).
__global__ void __launch_bounds__(256) k5(const float4* __restrict__ pp,
    const float4* __restrict__ gp, State* st, float* __restrict__ out) {
  __shared__ float4 sj[128];
  __shared__ double sdacc[4];
  const int tid = threadIdx.x;
  const int lane = tid & 63, wid = tid >> 6;
  int n = st->num_pos; if (n > MAX_POS) n = MAX_POS;
  const int jb = blockIdx.y << 7;
  if (tid < 128) {
    int j = jb + tid;
    sj[tid] = (j < n) ? pp[j] : make_float4(0.f, 0.f, 0.f, 0.f);
  }
  __syncthreads();
  const int i = (blockIdx.x << 8) + tid;
  double acc = 0.0;
  if (i < n) {
    float4 g = gp[i];
    int jend = n - jb; if (jend > 128) jend = 128;
    for (int j = 0; j < jend; ++j) {
      float4 p4 = sj[j];
      acc += (double)sl1(p4.x - g.x);
      acc += (double)sl1(p4.y - g.y);
      acc += (double)sl1(p4.z - g.z);
      acc += (double)sl1(p4.w - g.w);
    }
  }
  for (int off = 32; off > 0; off >>= 1) acc += __shfl_down(acc, off, 64);
  if (lane == 0) sdacc[wid] = acc;
  __syncthreads();
  if (tid == 0) {
    atomicAdd(&st->bbox_sum, sdacc[0] + sdacc[1] + sdacc[2] + sdacc[3]);
    __threadfence();
    u32 d = atomicAdd(&st->done, 1u);
    if (d == 8 * 16 - 1) {  // last block: all bbox_sum contributions visible
      __threadfence();
      int np = st->num_pos, nn = st->num_neg;
      int nsel = (np < nn) ? np : nn;
      double wsum = (double)(np + nsel);
      out[0] = (float)((st->sum_pos_ce + st->sum_neg_ce) / wsum);
      out[1] = (float)st->bbox_sum;
    }
  }
}

// ---------- launch ----------

extern "C" void kernel_launch(void* const* d_in, const int* in_sizes, int n_in,
                              void* d_out, int out_size, void* d_ws, size_t ws_size,
                              hipStream_t stream) {
  const float* rois   = (const float*)d_in[0];
  const float* scores = (const float*)d_in[1];
  const float* deltas = (const float*)d_in[2];
  const float4* gtb   = (const float4*)d_in[3];
  const int*   gtc    = (const int*)d_in[4];
  float* out = (float*)d_out;

  char* w = (char*)d_ws;
  // zero-init region: State | gkey | hist0 (~37KB memset)
  State* st    = (State*)w;   w += 256;
  u64* gkey    = (u64*)w;     w += (size_t)M_SZ * 8;
  u32* hist0   = (u32*)w;     w += (size_t)NBINS * 4;
  char* zero_end = w;
  // no-init scratch
  float4* pred = (float4*)w;  w += (size_t)L_SZ * 16;
  float* lse   = (float*)w;   w += (size_t)L_SZ * 4;
  u64* rowkey  = (u64*)w;     w += (size_t)L_SZ * 8;
  int* matches = (int*)w;     w += (size_t)L_SZ * 4;
  u32* neg_u   = (u32*)w;     w += (size_t)L_SZ * 4;
  int* blockcnt= (int*)w;     w += 256 * 4;
  float4* pp   = (float4*)w;  w += (size_t)MAX_POS * 16;
  float4* gp   = (float4*)w;  w += (size_t)MAX_POS * 16;

  hipMemsetAsync(d_ws, 0, (size_t)(zero_end - (char*)d_ws), stream);

  k1<<<L_SZ / 64, 256, 0, stream>>>(rois, scores, deltas, gtb, pred, lse, rowkey, gkey);
  k2<<<L_SZ / 256, 256, 0, stream>>>(rowkey, gkey, gtc, scores, lse, matches, neg_u,
                                     blockcnt, hist0, st);
  k3<<<L_SZ / 256, 256, 0, stream>>>(matches, pred, gtb, blockcnt, pp, gp);
  k4<<<L_SZ / 256, 256, 0, stream>>>(neg_u, hist0, scores, lse, st);
  k5<<<dim3(8, 16), 256, 0, stream>>>(pp, gp, st, out);
}

// Round 6
// 172.860 us; speedup vs baseline: 2.5405x; 1.3592x over previous
//
#include <hip/hip_runtime.h>
#include <stdint.h>

typedef unsigned int u32;
typedef unsigned long long u64;

#define F_UPPER 0.4f
#define F_LOWER 0.1f
#define MAX_POS 2048
#define L_SZ 65536
#define M_SZ 512
#define C_SZ 21
#define NBINS 8192
#define BIN_CAP 32
#define OVF_CAP 1024

struct State {
  double sum_pos_ce;
  double sum_neg_ce;
  double bbox_sum;
  int num_pos;
  int num_neg;
  u32 done;
  u32 _pad;
  u64 thresh;
};

__device__ __forceinline__ float area_fn(const float4 a) {
#pragma clang fp contract(off)
  return (a.z - a.x + 1.0f) * (a.w - a.y + 1.0f);
}

__device__ __forceinline__ float sl1(float d) {
#pragma clang fp contract(off)
  float ad = fabsf(d);
  return (ad < 0.01f) ? (50.0f * d * d) : (ad - 0.005f);
}

__device__ __forceinline__ u32 rotl(u32 x, int d) { return (x << d) | (x >> (32 - d)); }

// JAX threefry2x32, key=(0,42); counts = iota(L) split in halves.
__device__ u32 threefry_bits(u32 i, u32 H) {
  u32 x0, x1; bool hi;
  if (i < H) { x0 = i;     x1 = i + H; hi = false; }
  else       { x0 = i - H; x1 = i;     hi = true;  }
  const u32 ks0 = 0u, ks1 = 42u;
  const u32 ks2 = ks0 ^ ks1 ^ 0x1BD11BDAu;
  x0 += ks0; x1 += ks1;
#define RND(r) { x0 += x1; x1 = rotl(x1, r); x1 ^= x0; }
  RND(13) RND(15) RND(26) RND(6)   x0 += ks1; x1 += ks2 + 1u;
  RND(17) RND(29) RND(16) RND(24)  x0 += ks2; x1 += ks0 + 2u;
  RND(13) RND(15) RND(26) RND(6)   x0 += ks0; x1 += ks1 + 3u;
  RND(17) RND(29) RND(16) RND(24)  x0 += ks1; x1 += ks2 + 4u;
  RND(13) RND(15) RND(26) RND(6)   x0 += ks2; x1 += ks0 + 5u;
#undef RND
  return hi ? x1 : x0;
}

// ======== k1: ROI (argmax/lse/pred) + IoU row/col maxes. 1024 blocks x 64 preds x 512 gts.
__global__ void __launch_bounds__(256) k1(const float* __restrict__ rois,
    const float* __restrict__ scores, const float* __restrict__ deltas,
    const float4* __restrict__ gtb,
    float4* __restrict__ pred, float* __restrict__ lse,
    u64* __restrict__ rowkey, u64* __restrict__ gkey) {
  __shared__ float  ssc[64 * C_SZ];
  __shared__ float  sro[64 * 5];
  __shared__ float4 sg[M_SZ];
  __shared__ float  ga[M_SZ];
  __shared__ float4 spred[64];
  __shared__ float  sarea[64];
  __shared__ u64    srow[256];
  const int tid = threadIdx.x;
  const int pbase = blockIdx.x << 6;
  for (int k = tid; k < 64 * C_SZ; k += 256) ssc[k] = scores[(size_t)pbase * C_SZ + k];
  for (int k = tid; k < 64 * 5; k += 256)    sro[k] = rois[(size_t)pbase * 5 + k];
  for (int j = tid; j < M_SZ; j += 256) { float4 g = gtb[j]; sg[j] = g; ga[j] = area_fn(g); }
  __syncthreads();
  if (tid < 64) {
    const int i = pbase + tid;
    const float* sr = ssc + tid * C_SZ;
    float mx = sr[0]; int mi = 0;
    for (int j = 1; j < C_SZ; ++j) { float v = sr[j]; if (v > mx) { mx = v; mi = j; } }
    float s = 0.0f;
    for (int j = 0; j < C_SZ; ++j) s += expf(sr[j] - mx);
    lse[i] = mx + logf(s);
    // 16B-aligned gather: (84*i + 4*mi) floats is a multiple of 4 floats.
    float4 d = *(const float4*)(deltas + (size_t)i * (4 * C_SZ) + 4 * mi);
    const float* r = sro + tid * 5;
    float4 pb;
    pb.x = r[1] + d.x; pb.y = r[2] + d.y; pb.z = r[3] + d.z; pb.w = r[4] + d.w;
    spred[tid] = pb; sarea[tid] = area_fn(pb);
    pred[i] = pb;
  }
  __syncthreads();
  // Row phase: 4 threads per pred, 128 gts each (ascending j -> first-max tie-break).
  {
    const int p = tid & 63;
    const int j0 = (tid >> 6) << 7;
    const float4 pb = spred[p];
    const float pa = sarea[p];
    float rbest = -1.0f; int rbj = 0;
#pragma unroll 4
    for (int jj = 0; jj < 128; ++jj) {
#pragma clang fp contract(off)
      int j = j0 + jj;
      float4 gb = sg[j];
      float iw = fminf(pb.z, gb.z) - fmaxf(pb.x, gb.x) + 1.0f;
      iw = fmaxf(iw, 0.0f);
      float ih = fminf(pb.w, gb.w) - fmaxf(pb.y, gb.y) + 1.0f;
      ih = fmaxf(ih, 0.0f);
      float inter = iw * ih;
      float v = inter * __builtin_amdgcn_rcpf(pa + ga[j] - inter);
      if (v > rbest) { rbest = v; rbj = j; }
    }
    srow[tid] = ((u64)__float_as_uint(rbest) << 32) | (u32)(0xFFFFFFFFu - (u32)rbj);
  }
  __syncthreads();
  if (tid < 64) {
    u64 a = srow[tid], c = srow[tid + 64];
    u64 d = srow[tid + 128], e = srow[tid + 192];
    if (c > a) a = c;
    if (e > d) d = e;
    if (d > a) a = d;  // equal-float tie -> larger low32 = smaller j (first max)
    rowkey[pbase + tid] = a;
  }
  // Col phase: 2 gts/thread over this block's 64 preds; cross-block merge via atomicMax.
  for (int g = tid; g < M_SZ; g += 256) {
    const float4 gb = sg[g];
    const float gba = ga[g];
    float cbest = -1.0f; int cbp = 0;
#pragma unroll 4
    for (int p2 = 0; p2 < 64; ++p2) {
#pragma clang fp contract(off)
      float4 pb = spred[p2];
      float iw = fminf(pb.z, gb.z) - fmaxf(pb.x, gb.x) + 1.0f;
      iw = fmaxf(iw, 0.0f);
      float ih = fminf(pb.w, gb.w) - fmaxf(pb.y, gb.y) + 1.0f;
      ih = fmaxf(ih, 0.0f);
      float inter = iw * ih;
      float v = inter * __builtin_amdgcn_rcpf(sarea[p2] + gba - inter);
      if (v > cbest) { cbest = v; cbp = p2; }
    }
    u64 key = ((u64)__float_as_uint(cbest) << 32) | (u32)(0xFFFFFFFFu - (u32)(pbase + cbp));
    atomicMax(&gkey[g], key);
  }
}

// ======== k2: scat + match + pos CE + hist/bucket-store + blockcnt. 256 blocks.
__global__ void __launch_bounds__(256) k2(const u64* __restrict__ rowkey,
    const u64* __restrict__ gkey, const int* __restrict__ gtc,
    const float* __restrict__ scores, const float* __restrict__ lse,
    int* __restrict__ matches, u32* __restrict__ neg_u,
    int* __restrict__ blockcnt, u32* __restrict__ hist0, u64* __restrict__ bins,
    State* st) {
  __shared__ int sscat[256];
  __shared__ int swsum[4], sncnt[4];
  __shared__ double sdacc[4];
  const int tid = threadIdx.x;
  const int b = blockIdx.x;
  const int lane = tid & 63, wid = tid >> 6;
  sscat[tid] = -1;
  __syncthreads();
  for (int g = tid; g < M_SZ; g += 256) {
    u64 key = gkey[g];
    int pidx = (int)(0xFFFFFFFFu - (u32)key);
    if ((pidx >> 8) == b) atomicMax(&sscat[pidx & 255], g);  // dup idx_g: last (max g) wins
  }
  __syncthreads();
  const int i = (b << 8) + tid;
  u64 rk = rowkey[i];
  float best = __uint_as_float((u32)(rk >> 32));
  int idxp = (int)(0xFFFFFFFFu - (u32)rk);
  int m;
  if (best < F_LOWER) m = -2;
  else {
    int s = sscat[tid];
    m = (s >= 0) ? s : ((best >= F_UPPER) ? idxp : -1);
  }
  matches[i] = m;
  u32 ub = threefry_bits((u32)i, L_SZ >> 1) >> 9;
  neg_u[i] = (m == -2) ? ub : 0xFFFFFFFFu;
  float ce = 0.0f;
  if (m >= 0) {
    ce = lse[i] - scores[(size_t)i * C_SZ + gtc[m]];
  } else if (m == -2) {
    u32 bin = ub >> 10;
    u32 pos = atomicAdd(&hist0[bin], 1u);
    if (pos < BIN_CAP) bins[(size_t)bin * BIN_CAP + pos] = ((u64)ub << 16) | (u32)i;
  }
  u64 balp = __ballot(m >= 0);
  u64 baln = __ballot(m == -2);
  double acc = (double)ce;
  for (int off = 32; off > 0; off >>= 1) acc += __shfl_down(acc, off, 64);
  if (lane == 0) { swsum[wid] = __popcll(balp); sncnt[wid] = __popcll(baln); sdacc[wid] = acc; }
  __syncthreads();
  if (tid == 0) {
    int cp = swsum[0] + swsum[1] + swsum[2] + swsum[3];
    int cn = sncnt[0] + sncnt[1] + sncnt[2] + sncnt[3];
    blockcnt[b] = cp;
    atomicAdd(&st->num_pos, cp);
    atomicAdd(&st->num_neg, cn);
    atomicAdd(&st->sum_pos_ce, sdacc[0] + sdacc[1] + sdacc[2] + sdacc[3]);
  }
}

// ======== k3: ordered compaction (all blocks); block 0 also runs negative selection.
__global__ void __launch_bounds__(256) k3(const int* __restrict__ matches,
    const float4* __restrict__ pred, const float4* __restrict__ gtb,
    const int* __restrict__ blockcnt, float4* __restrict__ pp, float4* __restrict__ gp,
    const u32* __restrict__ hist0, const u64* __restrict__ bins,
    const u32* __restrict__ neg_u, State* st) {
  __shared__ int sscan[256];
  __shared__ int swsum[4];
  __shared__ int s_d, s_kk, s_cnt;
  __shared__ u32 s_ovf;
  __shared__ u64 sth;
  __shared__ u64 scand[OVF_CAP];
  const int tid = threadIdx.x, b = blockIdx.x;
  const int lane = tid & 63, wid = tid >> 6;
  // ---- compaction ----
  sscan[tid] = blockcnt[tid];
  __syncthreads();
  for (int off = 1; off < 256; off <<= 1) {
    int v = (tid >= off) ? sscan[tid - off] : 0;
    __syncthreads();
    sscan[tid] += v;
    __syncthreads();
  }
  int bpref = (b == 0) ? 0 : sscan[b - 1];
  if (bpref < MAX_POS) {  // block-uniform
    const int i = (b << 8) + tid;
    int m = matches[i];
    int flag = (m >= 0) ? 1 : 0;
    int incl = flag;
#pragma unroll
    for (int off = 1; off < 64; off <<= 1) {
      int v = __shfl_up(incl, off, 64);
      if (lane >= off) incl += v;
    }
    if (lane == 63) swsum[wid] = incl;
    __syncthreads();
    int wbase = 0;
    for (int w = 0; w < wid; ++w) wbase += swsum[w];
    int rank = bpref + wbase + incl - flag;
    if (flag && rank < MAX_POS) { pp[rank] = pred[i]; gp[rank] = gtb[m]; }
  }
  // ---- selection (block 0 only) ----
  if (b != 0) return;
  __syncthreads();
  const int np = st->num_pos, nn = st->num_neg;  // bg_num = round(np*1.0) = np
  if (np >= nn) {
    if (tid == 0) st->thresh = ~0ull;  // select all negatives
    return;
  }
  const uint4* h4 = (const uint4*)hist0;
  u32 loc[32]; int tsum = 0;
#pragma unroll
  for (int r = 0; r < 8; ++r) {
    uint4 v = h4[tid * 8 + r];
    loc[r*4] = v.x; loc[r*4+1] = v.y; loc[r*4+2] = v.z; loc[r*4+3] = v.w;
    tsum += v.x + v.y + v.z + v.w;
  }
  sscan[tid] = tsum;
  __syncthreads();
  for (int off = 1; off < 256; off <<= 1) {
    int v = (tid >= off) ? sscan[tid - off] : 0;
    __syncthreads();
    sscan[tid] += v;
    __syncthreads();
  }
  int incl = sscan[tid], excl = incl - tsum;
  if (np >= excl && np < incl) {
    int kk = np - excl; int d = 0, c = 0;
#pragma unroll
    for (int r = 0; r < 32; ++r) {
      if (kk < (int)loc[r]) { d = tid * 32 + r; c = (int)loc[r]; break; }
      kk -= (int)loc[r];
    }
    s_d = d; s_kk = kk; s_cnt = c;
  }
  if (tid == 0) s_ovf = 0;
  __syncthreads();
  const int d = s_d, kk = s_kk, cnt = s_cnt;
  if (cnt <= BIN_CAP) {
    // all bin-d keys are in the bucket store
    if (tid < cnt) scand[tid] = bins[(size_t)d * BIN_CAP + tid];
    __syncthreads();
    if (tid < cnt) {
      u64 key = scand[tid];
      int rank = 0;
      for (int u = 0; u < cnt; ++u) rank += (scand[u] < key) ? 1 : 0;
      if (rank == kk) sth = key;  // keys unique -> single writer
    }
  } else {
    // fallback (probability ~1e-12): sweep neg_u for bin-d keys
    for (int t = tid; t < L_SZ; t += 256) {
      u32 u = neg_u[t];
      if (u != 0xFFFFFFFFu && (int)(u >> 10) == d) {
        u32 pos = atomicAdd(&s_ovf, 1u);
        if (pos < OVF_CAP) scand[pos] = ((u64)u << 16) | (u32)t;
      }
    }
    __syncthreads();
    int c2 = (int)s_ovf; if (c2 > OVF_CAP) c2 = OVF_CAP;
    for (int t = tid; t < c2; t += 256) {
      u64 key = scand[t];
      int rank = 0;
      for (int u = 0; u < c2; ++u) rank += (scand[u] < key) ? 1 : 0;
      if (rank == kk) sth = key;
    }
  }
  __syncthreads();
  if (tid == 0) st->thresh = sth;  // select keys strictly below rank-bg_num key
}

// ======== k45: neg CE (all 256 blocks) + pair smooth-L1 (blocks 0..127) + final write.
__global__ void __launch_bounds__(256) k45(const u32* __restrict__ neg_u,
    const float* __restrict__ scores, const float* __restrict__ lse,
    const float4* __restrict__ pp, const float4* __restrict__ gp,
    State* st, float* __restrict__ out) {
  __shared__ float4 sj[128];
  __shared__ double sdacc[4];
  const int tid = threadIdx.x, b = blockIdx.x;
  const int lane = tid & 63, wid = tid >> 6;
  // ---- negative CE ----
  const u64 thresh = st->thresh;
  const int i = (b << 8) + tid;
  u32 u = neg_u[i];
  double acc = 0.0;
  if (u != 0xFFFFFFFFu) {
    u64 key = ((u64)u << 16) | (u32)i;
    if (key < thresh)
      acc = (double)(lse[i] - scores[(size_t)i * C_SZ + (C_SZ - 1)]);  // BACKGROUND=20
  }
  for (int off = 32; off > 0; off >>= 1) acc += __shfl_down(acc, off, 64);
  if (lane == 0) sdacc[wid] = acc;
  __syncthreads();
  if (tid == 0) atomicAdd(&st->sum_neg_ce, sdacc[0] + sdacc[1] + sdacc[2] + sdacc[3]);
  __syncthreads();
  // ---- pair loss (blocks 0..127 = 8 i-tiles x 16 j-tiles) ----
  if (b < 128) {
    int n = st->num_pos; if (n > MAX_POS) n = MAX_POS;
    const int jb = (b & 15) << 7;
    if (tid < 128) {
      int j = jb + tid;
      sj[tid] = (j < n) ? pp[j] : make_float4(0.f, 0.f, 0.f, 0.f);
    }
    __syncthreads();
    const int ii = ((b >> 4) << 8) + tid;
    double pacc = 0.0;
    if (ii < n) {
      float4 g = gp[ii];
      int jend = n - jb; if (jend > 128) jend = 128;
      for (int j = 0; j < jend; ++j) {
        float4 p4 = sj[j];
        pacc += (double)sl1(p4.x - g.x);
        pacc += (double)sl1(p4.y - g.y);
        pacc += (double)sl1(p4.z - g.z);
        pacc += (double)sl1(p4.w - g.w);
      }
    }
    for (int off = 32; off > 0; off >>= 1) pacc += __shfl_down(pacc, off, 64);
    if (lane == 0) sdacc[wid] = pacc;
    __syncthreads();
    if (tid == 0) atomicAdd(&st->bbox_sum, sdacc[0] + sdacc[1] + sdacc[2] + sdacc[3]);
  }
  // ---- last block writes final outputs ----
  if (tid == 0) {
    __threadfence();
    u32 dn = atomicAdd(&st->done, 1u);
    if (dn == 255) {
      __threadfence();
      int np = st->num_pos, nn = st->num_neg;
      int nsel = (np < nn) ? np : nn;
      double wsum = (double)(np + nsel);
      out[0] = (float)((st->sum_pos_ce + st->sum_neg_ce) / wsum);
      out[1] = (float)st->bbox_sum;
    }
  }
}

// ---------- launch ----------

extern "C" void kernel_launch(void* const* d_in, const int* in_sizes, int n_in,
                              void* d_out, int out_size, void* d_ws, size_t ws_size,
                              hipStream_t stream) {
  const float* rois   = (const float*)d_in[0];
  const float* scores = (const float*)d_in[1];
  const float* deltas = (const float*)d_in[2];
  const float4* gtb   = (const float4*)d_in[3];
  const int*   gtc    = (const int*)d_in[4];
  float* out = (float*)d_out;

  char* w = (char*)d_ws;
  // zero-init region: State | gkey | hist0 (~37KB memset)
  State* st    = (State*)w;   w += 256;
  u64* gkey    = (u64*)w;     w += (size_t)M_SZ * 8;
  u32* hist0   = (u32*)w;     w += (size_t)NBINS * 4;
  char* zero_end = w;
  // no-init scratch
  u64* bins    = (u64*)w;     w += (size_t)NBINS * BIN_CAP * 8;  // 2MB bucket store
  float4* pred = (float4*)w;  w += (size_t)L_SZ * 16;
  float* lse   = (float*)w;   w += (size_t)L_SZ * 4;
  u64* rowkey  = (u64*)w;     w += (size_t)L_SZ * 8;
  int* matches = (int*)w;     w += (size_t)L_SZ * 4;
  u32* neg_u   = (u32*)w;     w += (size_t)L_SZ * 4;
  int* blockcnt= (int*)w;     w += 256 * 4;
  float4* pp   = (float4*)w;  w += (size_t)MAX_POS * 16;
  float4* gp   = (float4*)w;  w += (size_t)MAX_POS * 16;

  hipMemsetAsync(d_ws, 0, (size_t)(zero_end - (char*)d_ws), stream);

  k1<<<L_SZ / 64, 256, 0, stream>>>(rois, scores, deltas, gtb, pred, lse, rowkey, gkey);
  k2<<<L_SZ / 256, 256, 0, stream>>>(rowkey, gkey, gtc, scores, lse, matches, neg_u,
                                     blockcnt, hist0, bins, st);
  k3<<<L_SZ / 256, 256, 0, stream>>>(matches, pred, gtb, blockcnt, pp, gp,
                                     hist0, bins, neg_u, st);
  k45<<<L_SZ / 256, 256, 0, stream>>>(neg_u, scores, lse, pp, gp, st, out);
}